// Round 1
// baseline (3111.392 us; speedup 1.0000x reference)
//
#include <hip/hip_runtime.h>

// ---------------------------------------------------------------------------
// DecoderBackbone: 4-layer llama-style decoder, B=2 T=1024 HID=2048,
// NH=16 NKV=4 HD=128, INTER=5632. fp32 residual stream, bf16 MFMA GEMMs.
// ---------------------------------------------------------------------------

typedef __attribute__((ext_vector_type(8))) __bf16 bf16x8;
typedef __attribute__((ext_vector_type(4))) float f32x4;
typedef __attribute__((ext_vector_type(4))) unsigned short u16x4;

#define DEV __device__ __forceinline__

#define NTOK 2048     // B*T
#define HIDDIM 2048
#define NHEADS 16
#define NKVH 4
#define HDIM 128
#define KVDIM 512     // NKV*HD
#define INTERDIM 5632

DEV unsigned short f2bf(float f) {
  union { float f; unsigned u; } a; a.f = f;
  unsigned r = a.u + 0x7fffu + ((a.u >> 16) & 1u);   // RNE
  return (unsigned short)(r >> 16);
}
DEV float bf2f(unsigned short h) {
  union { unsigned u; float f; } a; a.u = ((unsigned)h) << 16;
  return a.f;
}
DEV void gload_lds16(const void* g, void* l) {
  __builtin_amdgcn_global_load_lds(
      (const __attribute__((address_space(1))) unsigned int*)(g),
      (__attribute__((address_space(3))) unsigned int*)(l), 16, 0, 0);
}

// ---------------------------------------------------------------------------
// RMSNorm: x fp32 [row][2048] -> out (bf16 or fp32), one block per row.
// ---------------------------------------------------------------------------
template <int OUTF32>
__global__ __launch_bounds__(256) void rmsnorm_kernel(
    const float* __restrict__ x, const float* __restrict__ w,
    void* __restrict__ outp) {
  const int row = blockIdx.x, tid = threadIdx.x;
  const int lane = tid & 63, wave = tid >> 6;
  const float* xr = x + (size_t)row * HIDDIM;
  f32x4 v0 = *reinterpret_cast<const f32x4*>(xr + tid * 4);
  f32x4 v1 = *reinterpret_cast<const f32x4*>(xr + 1024 + tid * 4);
  float ss = v0.x * v0.x + v0.y * v0.y + v0.z * v0.z + v0.w * v0.w +
             v1.x * v1.x + v1.y * v1.y + v1.z * v1.z + v1.w * v1.w;
#pragma unroll
  for (int off = 1; off < 64; off <<= 1) ss += __shfl_xor(ss, off, 64);
  __shared__ float red[4];
  if (lane == 0) red[wave] = ss;
  __syncthreads();
  ss = red[0] + red[1] + red[2] + red[3];
  const float rs = rsqrtf(ss * (1.0f / 2048.0f) + 1e-6f);
  f32x4 w0 = *reinterpret_cast<const f32x4*>(w + tid * 4);
  f32x4 w1 = *reinterpret_cast<const f32x4*>(w + 1024 + tid * 4);
  if (OUTF32) {
    float* o = (float*)outp + (size_t)row * HIDDIM;
    f32x4 o0, o1;
    o0.x = v0.x * rs * w0.x; o0.y = v0.y * rs * w0.y;
    o0.z = v0.z * rs * w0.z; o0.w = v0.w * rs * w0.w;
    o1.x = v1.x * rs * w1.x; o1.y = v1.y * rs * w1.y;
    o1.z = v1.z * rs * w1.z; o1.w = v1.w * rs * w1.w;
    *reinterpret_cast<f32x4*>(o + tid * 4) = o0;
    *reinterpret_cast<f32x4*>(o + 1024 + tid * 4) = o1;
  } else {
    unsigned short* o = (unsigned short*)outp + (size_t)row * HIDDIM;
    u16x4 p0, p1;
    p0.x = f2bf(v0.x * rs * w0.x); p0.y = f2bf(v0.y * rs * w0.y);
    p0.z = f2bf(v0.z * rs * w0.z); p0.w = f2bf(v0.w * rs * w0.w);
    p1.x = f2bf(v1.x * rs * w1.x); p1.y = f2bf(v1.y * rs * w1.y);
    p1.z = f2bf(v1.z * rs * w1.z); p1.w = f2bf(v1.w * rs * w1.w);
    *reinterpret_cast<u16x4*>(o + tid * 4) = p0;
    *reinterpret_cast<u16x4*>(o + 1024 + tid * 4) = p1;
  }
}

// ---------------------------------------------------------------------------
// GEMM core: C[128x128] += A[MxK](bf16,row-major) * W[NxK](fp32,row-major)^T
// m97 structure: BK=32, 4 waves of 64x64, A staged via global_load_lds(16B),
// W reg-staged with fp32->bf16 convert.
// ---------------------------------------------------------------------------
DEV void gemm_core(const unsigned short* __restrict__ A,
                   const float* __restrict__ W, int K, int m0, int n0,
                   unsigned short* sA, unsigned short* sB,
                   f32x4 (&acc)[4][4]) {
  const int tid = threadIdx.x;
  const int lane = tid & 63, wave = tid >> 6;
  const int fr = lane & 15, kq = (lane >> 4) * 8;
  const int wr = (wave >> 1) * 64, wc = (wave & 1) * 64;
  // A staging: 128x32 bf16 = 8KB, 2x global_load_lds of 16B per thread
  const int a_row = tid >> 2, a_kk = (tid & 3) * 8;
  const unsigned short* Ag0 = A + (size_t)(m0 + a_row) * K + a_kk;
  const unsigned short* Ag1 = Ag0 + (size_t)64 * K;
  unsigned short* sA0 = sA + wave * 512;
  unsigned short* sA1 = sA + 2048 + wave * 512;
  // B staging: 128x32 fp32 -> bf16, 4x float4 per thread
  const int b_row = tid >> 3, b_kk = (tid & 7) * 4;
  const float* Wg = W + (size_t)(n0 + b_row) * K + b_kk;
  unsigned short* sBw = sB + b_row * 32 + b_kk;

  for (int k0 = 0; k0 < K; k0 += 32) {
    gload_lds16(Ag0 + k0, sA0);
    gload_lds16(Ag1 + k0, sA1);
#pragma unroll
    for (int j = 0; j < 4; ++j) {
      f32x4 wv = *reinterpret_cast<const f32x4*>(Wg + (size_t)(j * 32) * K + k0);
      u16x4 pk;
      pk.x = f2bf(wv.x); pk.y = f2bf(wv.y);
      pk.z = f2bf(wv.z); pk.w = f2bf(wv.w);
      *reinterpret_cast<u16x4*>(sBw + j * 1024) = pk;
    }
    __syncthreads();
    bf16x8 af[4], bfr[4];
#pragma unroll
    for (int i = 0; i < 4; ++i)
      af[i] = *reinterpret_cast<const bf16x8*>(sA + (wr + i * 16 + fr) * 32 + kq);
#pragma unroll
    for (int i = 0; i < 4; ++i)
      bfr[i] = *reinterpret_cast<const bf16x8*>(sB + (wc + i * 16 + fr) * 32 + kq);
#pragma unroll
    for (int mi = 0; mi < 4; ++mi)
#pragma unroll
      for (int ni = 0; ni < 4; ++ni)
        acc[mi][ni] = __builtin_amdgcn_mfma_f32_16x16x32_bf16(
            af[mi], bfr[ni], acc[mi][ni], 0, 0, 0);
    __syncthreads();
  }
}

// EPI: 0 = bf16 store (+bias), 1 = fp32 residual add into xres, 2 = silu(gate)*acc
template <int EPI>
__global__ __launch_bounds__(256) void gemm_bt(
    const unsigned short* __restrict__ A, const float* __restrict__ W,
    const float* __restrict__ bias, unsigned short* __restrict__ outb,
    float* __restrict__ xres, const unsigned short* __restrict__ gate,
    int K, int ldo) {
  __shared__ unsigned short sA[4096];
  __shared__ unsigned short sB[4096];
  f32x4 acc[4][4] = {};
  const int m0 = blockIdx.y * 128, n0 = blockIdx.x * 128;
  gemm_core(A, W, K, m0, n0, sA, sB, acc);
  const int lane = threadIdx.x & 63, wave = threadIdx.x >> 6;
  const int fr = lane & 15, r0 = (lane >> 4) * 4;
  const int wr = (wave >> 1) * 64, wc = (wave & 1) * 64;
#pragma unroll
  for (int mi = 0; mi < 4; ++mi)
#pragma unroll
    for (int ni = 0; ni < 4; ++ni)
#pragma unroll
      for (int r = 0; r < 4; ++r) {
        const int gm = m0 + wr + mi * 16 + r0 + r;
        const int gn = n0 + wc + ni * 16 + fr;
        float v = acc[mi][ni][r];
        if (EPI == 0) {
          if (bias) v += bias[gn];
          outb[(size_t)gm * ldo + gn] = f2bf(v);
        } else if (EPI == 1) {
          xres[(size_t)gm * ldo + gn] += v;
        } else {
          const float g = bf2f(gate[(size_t)gm * ldo + gn]);
          const float s = g / (1.f + __expf(-g));
          outb[(size_t)gm * ldo + gn] = f2bf(s * v);
        }
      }
}

// Fused QKV: col-tiles 0..15 -> q, 16..19 -> k, 20..23 -> v
__global__ __launch_bounds__(256) void gemm_qkv(
    const unsigned short* __restrict__ A, const float* __restrict__ qw,
    const float* __restrict__ qbias, const float* __restrict__ kw,
    const float* __restrict__ kbias, const float* __restrict__ vw,
    const float* __restrict__ vbias, unsigned short* __restrict__ qo,
    unsigned short* __restrict__ ko, unsigned short* __restrict__ vo) {
  __shared__ unsigned short sA[4096];
  __shared__ unsigned short sB[4096];
  const int ct = blockIdx.x;
  const float* W; const float* bias; unsigned short* out; int n0, ldo;
  if (ct < 16)      { W = qw; bias = qbias; out = qo; n0 = ct * 128;        ldo = HIDDIM; }
  else if (ct < 20) { W = kw; bias = kbias; out = ko; n0 = (ct - 16) * 128; ldo = KVDIM; }
  else              { W = vw; bias = vbias; out = vo; n0 = (ct - 20) * 128; ldo = KVDIM; }
  f32x4 acc[4][4] = {};
  const int m0 = blockIdx.y * 128;
  gemm_core(A, W, HIDDIM, m0, n0, sA, sB, acc);
  const int lane = threadIdx.x & 63, wave = threadIdx.x >> 6;
  const int fr = lane & 15, r0 = (lane >> 4) * 4;
  const int wr = (wave >> 1) * 64, wc = (wave & 1) * 64;
#pragma unroll
  for (int mi = 0; mi < 4; ++mi)
#pragma unroll
    for (int ni = 0; ni < 4; ++ni)
#pragma unroll
      for (int r = 0; r < 4; ++r) {
        const int gm = m0 + wr + mi * 16 + r0 + r;
        const int gn = n0 + wc + ni * 16 + fr;
        out[(size_t)gm * ldo + gn] = f2bf(acc[mi][ni][r] + bias[gn]);
      }
}

// ---------------------------------------------------------------------------
// RoPE, in place on q (16 heads) and k (4 heads). 64 threads per (tok,head);
// thread d owns the (d, d+64) pair, so no sync needed.
// ---------------------------------------------------------------------------
__global__ __launch_bounds__(256) void rope_kernel(
    unsigned short* __restrict__ q, unsigned short* __restrict__ k,
    const float* __restrict__ cosb, const float* __restrict__ sinb) {
  const int slot = blockIdx.x * 4 + (threadIdx.x >> 6);
  const int d = threadIdx.x & 63;
  const int tok = slot / 20, hs = slot % 20;
  unsigned short* base;
  if (hs < 16) base = q + (size_t)tok * HIDDIM + hs * HDIM;
  else         base = k + (size_t)tok * KVDIM + (hs - 16) * HDIM;
  const float c1 = cosb[(size_t)tok * HDIM + d];
  const float s1 = sinb[(size_t)tok * HDIM + d];
  const float c2 = cosb[(size_t)tok * HDIM + d + 64];
  const float s2 = sinb[(size_t)tok * HDIM + d + 64];
  const float x1 = bf2f(base[d]), x2 = bf2f(base[d + 64]);
  base[d]      = f2bf(x1 * c1 - x2 * s1);
  base[d + 64] = f2bf(x2 * c2 + x1 * s2);
}

// v[tok][kvh*128+d] -> vt[(b*4+kvh)*128+d][t]   (output-coalesced)
__global__ __launch_bounds__(256) void transpose_v(
    const unsigned short* __restrict__ v, unsigned short* __restrict__ vt) {
  const int o = blockIdx.x * 256 + threadIdx.x;   // < 1048576
  const int t = o & 1023;
  const int rest = o >> 10;          // (b*4+kvh)*128 + d
  const int d = rest & 127;
  const int bh = rest >> 7;          // 0..7
  const int kvh = bh & 3, b = bh >> 2;
  vt[o] = v[(size_t)(b * 1024 + t) * KVDIM + kvh * HDIM + d];
}

// ---------------------------------------------------------------------------
// Flash attention, causal, GQA. Block = 4 waves; wave owns 16 q-rows.
// KV iterated in 64-col blocks; K/V read direct from global (L2-resident),
// P staged per-wave through LDS. fp32 online softmax.
// ---------------------------------------------------------------------------
__global__ __launch_bounds__(256) void attn_kernel(
    const unsigned short* __restrict__ q, const unsigned short* __restrict__ k,
    const unsigned short* __restrict__ vt, unsigned short* __restrict__ ao) {
  __shared__ unsigned short P_lds[4][1024];   // [wave][16q x 64kv]
  const int tid = threadIdx.x, lane = tid & 63, wave = tid >> 6;
  const int qt = blockIdx.x, h = blockIdx.y, b = blockIdx.z;
  const int kvh = h >> 2;
  const int q0 = qt * 64 + wave * 16;
  const int tokbase = b * 1024;
  const int fr = lane & 15, kq = (lane >> 4) * 8, r0 = (lane >> 4) * 4;

  bf16x8 aQ[4];
  {
    const unsigned short* qp =
        q + (size_t)(tokbase + q0 + fr) * HIDDIM + h * HDIM + kq;
#pragma unroll
    for (int ds = 0; ds < 4; ++ds)
      aQ[ds] = *reinterpret_cast<const bf16x8*>(qp + ds * 32);
  }
  float mrow[4], lrow[4];
#pragma unroll
  for (int r = 0; r < 4; ++r) { mrow[r] = -1e30f; lrow[r] = 0.f; }
  f32x4 accO[8] = {};
  const float scale = 0.08838834764831845f;   // 1/sqrt(128)
  const unsigned short* vbase = vt + (size_t)(b * 4 + kvh) * 128 * 1024;
  unsigned short* pw = &P_lds[wave][0];

  for (int kb = 0; kb <= qt; ++kb) {
    const int kv0 = kb * 64;
    f32x4 sacc[4] = {};
    const unsigned short* kbp =
        k + (size_t)(tokbase + kv0) * KVDIM + kvh * HDIM;
#pragma unroll
    for (int cb = 0; cb < 4; ++cb) {
      const unsigned short* kr = kbp + (size_t)(cb * 16 + fr) * KVDIM + kq;
#pragma unroll
      for (int ds = 0; ds < 4; ++ds) {
        bf16x8 bK = *reinterpret_cast<const bf16x8*>(kr + ds * 32);
        sacc[cb] =
            __builtin_amdgcn_mfma_f32_16x16x32_bf16(aQ[ds], bK, sacc[cb], 0, 0, 0);
      }
    }
    const bool maskblk = (kb == qt);
    float p[4][4];
#pragma unroll
    for (int r = 0; r < 4; ++r) {
      const int grow = q0 + r0 + r;
      float mx = -1e30f;
#pragma unroll
      for (int cb = 0; cb < 4; ++cb) {
        float s = sacc[cb][r] * scale;
        if (maskblk && (kv0 + cb * 16 + fr > grow)) s = -1e30f;
        p[cb][r] = s;
        mx = fmaxf(mx, s);
      }
#pragma unroll
      for (int off = 1; off < 16; off <<= 1)
        mx = fmaxf(mx, __shfl_xor(mx, off, 64));
      const float mn = fmaxf(mrow[r], mx);
      const float alpha = __expf(mrow[r] - mn);
      float sum = 0.f;
#pragma unroll
      for (int cb = 0; cb < 4; ++cb) {
        const float e = __expf(p[cb][r] - mn);
        p[cb][r] = e; sum += e;
      }
#pragma unroll
      for (int off = 1; off < 16; off <<= 1) sum += __shfl_xor(sum, off, 64);
      lrow[r] = lrow[r] * alpha + sum;
      mrow[r] = mn;
#pragma unroll
      for (int db = 0; db < 8; ++db) accO[db][r] *= alpha;
    }
    // P -> per-wave LDS (compiler orders ds_write -> ds_read via lgkmcnt)
#pragma unroll
    for (int cb = 0; cb < 4; ++cb)
#pragma unroll
      for (int r = 0; r < 4; ++r)
        pw[(r0 + r) * 64 + cb * 16 + fr] = f2bf(p[cb][r]);
    bf16x8 aP[2];
#pragma unroll
    for (int s2 = 0; s2 < 2; ++s2)
      aP[s2] = *reinterpret_cast<const bf16x8*>(pw + fr * 64 + s2 * 32 + kq);
#pragma unroll
    for (int db = 0; db < 8; ++db) {
      const unsigned short* vr = vbase + (size_t)(db * 16 + fr) * 1024 + kv0 + kq;
#pragma unroll
      for (int s2 = 0; s2 < 2; ++s2) {
        bf16x8 bV = *reinterpret_cast<const bf16x8*>(vr + s2 * 32);
        accO[db] =
            __builtin_amdgcn_mfma_f32_16x16x32_bf16(aP[s2], bV, accO[db], 0, 0, 0);
      }
    }
  }
  float invl[4];
#pragma unroll
  for (int r = 0; r < 4; ++r) invl[r] = 1.f / lrow[r];
#pragma unroll
  for (int db = 0; db < 8; ++db)
#pragma unroll
    for (int r = 0; r < 4; ++r)
      ao[(size_t)(tokbase + q0 + r0 + r) * HIDDIM + h * HDIM + db * 16 + fr] =
          f2bf(accO[db][r] * invl[r]);
}

// ---------------------------------------------------------------------------
extern "C" void kernel_launch(void* const* d_in, const int* in_sizes, int n_in,
                              void* d_out, int out_size, void* d_ws,
                              size_t ws_size, hipStream_t stream) {
  (void)in_sizes; (void)n_in; (void)out_size; (void)ws_size;
  const float* hidden = (const float*)d_in[0];
  const float* cosb  = (const float*)d_in[1];
  const float* sinb  = (const float*)d_in[2];
  const float* qw    = (const float*)d_in[3];
  const float* qbias = (const float*)d_in[4];
  const float* kw    = (const float*)d_in[5];
  const float* kbias = (const float*)d_in[6];
  const float* vw    = (const float*)d_in[7];
  const float* vbias = (const float*)d_in[8];
  const float* ow    = (const float*)d_in[9];
  const float* gw    = (const float*)d_in[10];
  const float* uw    = (const float*)d_in[11];
  const float* dw    = (const float*)d_in[12];
  const float* ln1   = (const float*)d_in[13];
  const float* ln2   = (const float*)d_in[14];
  const float* normw = (const float*)d_in[15];

  char* ws = (char*)d_ws;
  float* x               = (float*)ws;                          // 16,777,216 B
  unsigned short* hbuf   = (unsigned short*)(ws + 16777216);    //  8,388,608
  unsigned short* qbuf   = (unsigned short*)(ws + 25165824);    //  8,388,608
  unsigned short* kbuf   = (unsigned short*)(ws + 33554432);    //  2,097,152
  unsigned short* vbuf   = (unsigned short*)(ws + 35651584);    //  2,097,152
  unsigned short* vtbuf  = (unsigned short*)(ws + 37748736);    //  2,097,152
  unsigned short* aobuf  = (unsigned short*)(ws + 39845888);    //  8,388,608
  unsigned short* gatebuf= (unsigned short*)(ws + 48234496);    // 23,068,672
  unsigned short* actbuf = (unsigned short*)(ws + 71303168);    // 23,068,672
  // total: 94,371,840 bytes

  hipMemcpyAsync(x, hidden, (size_t)NTOK * HIDDIM * 4,
                 hipMemcpyDeviceToDevice, stream);

  for (int l = 0; l < 4; ++l) {
    const float* qw_l = qw + (size_t)l * 2048 * 2048;
    const float* qb_l = qbias + (size_t)l * 2048;
    const float* kw_l = kw + (size_t)l * 512 * 2048;
    const float* kb_l = kbias + (size_t)l * 512;
    const float* vw_l = vw + (size_t)l * 512 * 2048;
    const float* vb_l = vbias + (size_t)l * 512;
    const float* ow_l = ow + (size_t)l * 2048 * 2048;
    const float* gw_l = gw + (size_t)l * 5632 * 2048;
    const float* uw_l = uw + (size_t)l * 5632 * 2048;
    const float* dw_l = dw + (size_t)l * 2048 * 5632;

    rmsnorm_kernel<0><<<NTOK, 256, 0, stream>>>(x, ln1 + l * 2048, hbuf);
    gemm_qkv<<<dim3(24, 16), 256, 0, stream>>>(hbuf, qw_l, qb_l, kw_l, kb_l,
                                               vw_l, vb_l, qbuf, kbuf, vbuf);
    rope_kernel<<<10240, 256, 0, stream>>>(qbuf, kbuf, cosb, sinb);
    transpose_v<<<4096, 256, 0, stream>>>(vbuf, vtbuf);
    attn_kernel<<<dim3(16, 16, 2), 256, 0, stream>>>(qbuf, kbuf, vtbuf, aobuf);
    gemm_bt<1><<<dim3(16, 16), 256, 0, stream>>>(aobuf, ow_l, nullptr, nullptr,
                                                 x, nullptr, 2048, 2048);
    rmsnorm_kernel<0><<<NTOK, 256, 0, stream>>>(x, ln2 + l * 2048, hbuf);
    gemm_bt<0><<<dim3(44, 16), 256, 0, stream>>>(hbuf, gw_l, nullptr, gatebuf,
                                                 nullptr, nullptr, 2048, 5632);
    gemm_bt<2><<<dim3(44, 16), 256, 0, stream>>>(hbuf, uw_l, nullptr, actbuf,
                                                 nullptr, gatebuf, 2048, 5632);
    gemm_bt<1><<<dim3(16, 16), 256, 0, stream>>>(actbuf, dw_l, nullptr, nullptr,
                                                 x, nullptr, 5632, 2048);
  }
  rmsnorm_kernel<1><<<NTOK, 256, 0, stream>>>(x, normw, d_out);
}

// Round 2
// 2422.969 us; speedup vs baseline: 1.2841x; 1.2841x over previous
//
#include <hip/hip_runtime.h>

// ---------------------------------------------------------------------------
// DecoderBackbone: 4-layer llama-style decoder, B=2 T=1024 HID=2048,
// NH=16 NKV=4 HD=128, INTER=5632. fp32 residual stream, bf16 MFMA GEMMs.
// R2: weights pre-converted fp32->bf16 per phase; GEMM = pure-bf16 m97
// structure (global_load_lds both operands) + XCD-swizzled block mapping.
// ---------------------------------------------------------------------------

typedef __attribute__((ext_vector_type(8))) __bf16 bf16x8;
typedef __attribute__((ext_vector_type(4))) float f32x4;
typedef __attribute__((ext_vector_type(4))) unsigned short u16x4;

#define DEV __device__ __forceinline__

#define NTOK 2048     // B*T
#define HIDDIM 2048
#define NHEADS 16
#define NKVH 4
#define HDIM 128
#define KVDIM 512     // NKV*HD
#define INTERDIM 5632

DEV unsigned short f2bf(float f) {
  union { float f; unsigned u; } a; a.f = f;
  unsigned r = a.u + 0x7fffu + ((a.u >> 16) & 1u);   // RNE
  return (unsigned short)(r >> 16);
}
DEV float bf2f(unsigned short h) {
  union { unsigned u; float f; } a; a.u = ((unsigned)h) << 16;
  return a.f;
}
DEV void gload_lds16(const void* g, void* l) {
  __builtin_amdgcn_global_load_lds(
      (const __attribute__((address_space(1))) unsigned int*)(g),
      (__attribute__((address_space(3))) unsigned int*)(l), 16, 0, 0);
}

// ---------------------------------------------------------------------------
// fp32 -> bf16 weight convert, 8 elems/thread. n8 = n/8 (all sizes % 8 == 0).
// ---------------------------------------------------------------------------
__global__ __launch_bounds__(256) void cvt_kernel(
    const float* __restrict__ in, unsigned short* __restrict__ out, int n8) {
  const int i = blockIdx.x * 256 + threadIdx.x;
  if (i >= n8) return;
  const f32x4* p = reinterpret_cast<const f32x4*>(in) + (size_t)i * 2;
  const f32x4 a = p[0], b = p[1];
  bf16x8 o;
  o[0] = (__bf16)a.x; o[1] = (__bf16)a.y; o[2] = (__bf16)a.z; o[3] = (__bf16)a.w;
  o[4] = (__bf16)b.x; o[5] = (__bf16)b.y; o[6] = (__bf16)b.z; o[7] = (__bf16)b.w;
  *reinterpret_cast<bf16x8*>(out + (size_t)i * 8) = o;
}

// ---------------------------------------------------------------------------
// RMSNorm: x fp32 [row][2048] -> out (bf16 or fp32), one block per row.
// ---------------------------------------------------------------------------
template <int OUTF32>
__global__ __launch_bounds__(256) void rmsnorm_kernel(
    const float* __restrict__ x, const float* __restrict__ w,
    void* __restrict__ outp) {
  const int row = blockIdx.x, tid = threadIdx.x;
  const int lane = tid & 63, wave = tid >> 6;
  const float* xr = x + (size_t)row * HIDDIM;
  f32x4 v0 = *reinterpret_cast<const f32x4*>(xr + tid * 4);
  f32x4 v1 = *reinterpret_cast<const f32x4*>(xr + 1024 + tid * 4);
  float ss = v0.x * v0.x + v0.y * v0.y + v0.z * v0.z + v0.w * v0.w +
             v1.x * v1.x + v1.y * v1.y + v1.z * v1.z + v1.w * v1.w;
#pragma unroll
  for (int off = 1; off < 64; off <<= 1) ss += __shfl_xor(ss, off, 64);
  __shared__ float red[4];
  if (lane == 0) red[wave] = ss;
  __syncthreads();
  ss = red[0] + red[1] + red[2] + red[3];
  const float rs = rsqrtf(ss * (1.0f / 2048.0f) + 1e-6f);
  f32x4 w0 = *reinterpret_cast<const f32x4*>(w + tid * 4);
  f32x4 w1 = *reinterpret_cast<const f32x4*>(w + 1024 + tid * 4);
  if (OUTF32) {
    float* o = (float*)outp + (size_t)row * HIDDIM;
    f32x4 o0, o1;
    o0.x = v0.x * rs * w0.x; o0.y = v0.y * rs * w0.y;
    o0.z = v0.z * rs * w0.z; o0.w = v0.w * rs * w0.w;
    o1.x = v1.x * rs * w1.x; o1.y = v1.y * rs * w1.y;
    o1.z = v1.z * rs * w1.z; o1.w = v1.w * rs * w1.w;
    *reinterpret_cast<f32x4*>(o + tid * 4) = o0;
    *reinterpret_cast<f32x4*>(o + 1024 + tid * 4) = o1;
  } else {
    unsigned short* o = (unsigned short*)outp + (size_t)row * HIDDIM;
    u16x4 p0, p1;
    p0.x = f2bf(v0.x * rs * w0.x); p0.y = f2bf(v0.y * rs * w0.y);
    p0.z = f2bf(v0.z * rs * w0.z); p0.w = f2bf(v0.w * rs * w0.w);
    p1.x = f2bf(v1.x * rs * w1.x); p1.y = f2bf(v1.y * rs * w1.y);
    p1.z = f2bf(v1.z * rs * w1.z); p1.w = f2bf(v1.w * rs * w1.w);
    *reinterpret_cast<u16x4*>(o + tid * 4) = p0;
    *reinterpret_cast<u16x4*>(o + 1024 + tid * 4) = p1;
  }
}

// ---------------------------------------------------------------------------
// GEMM core (m97 structure): C[128x128] += A[MxK] * W[NxK]^T, both bf16
// row-major. BK=32, 4 waves of 64x64, both operands via global_load_lds(16B),
// 2-barrier K-loop.
// ---------------------------------------------------------------------------
DEV void gemm_core(const unsigned short* __restrict__ A,
                   const unsigned short* __restrict__ Wb, int K, int m0, int n0,
                   unsigned short* sA, unsigned short* sB,
                   f32x4 (&acc)[4][4]) {
  const int tid = threadIdx.x;
  const int lane = tid & 63, wave = tid >> 6;
  const int fr = lane & 15, kq = (lane >> 4) * 8;
  const int wr = (wave >> 1) * 64, wc = (wave & 1) * 64;
  // staging: 128x32 bf16 = 8KB per operand; thread -> (row = tid>>2, 8 elems)
  const int row = tid >> 2, kk = (tid & 3) * 8;
  const unsigned short* Ag0 = A + (size_t)(m0 + row) * K + kk;
  const unsigned short* Ag1 = Ag0 + (size_t)64 * K;
  const unsigned short* Bg0 = Wb + (size_t)(n0 + row) * K + kk;
  const unsigned short* Bg1 = Bg0 + (size_t)64 * K;
  unsigned short* sA0 = sA + wave * 512;
  unsigned short* sA1 = sA + 2048 + wave * 512;
  unsigned short* sB0 = sB + wave * 512;
  unsigned short* sB1 = sB + 2048 + wave * 512;

  for (int k0 = 0; k0 < K; k0 += 32) {
    gload_lds16(Ag0 + k0, sA0);
    gload_lds16(Ag1 + k0, sA1);
    gload_lds16(Bg0 + k0, sB0);
    gload_lds16(Bg1 + k0, sB1);
    __syncthreads();
    bf16x8 af[4], bfr[4];
#pragma unroll
    for (int i = 0; i < 4; ++i)
      af[i] = *reinterpret_cast<const bf16x8*>(sA + (wr + i * 16 + fr) * 32 + kq);
#pragma unroll
    for (int i = 0; i < 4; ++i)
      bfr[i] = *reinterpret_cast<const bf16x8*>(sB + (wc + i * 16 + fr) * 32 + kq);
#pragma unroll
    for (int mi = 0; mi < 4; ++mi)
#pragma unroll
      for (int ni = 0; ni < 4; ++ni)
        acc[mi][ni] = __builtin_amdgcn_mfma_f32_16x16x32_bf16(
            af[mi], bfr[ni], acc[mi][ni], 0, 0, 0);
    __syncthreads();
  }
}

// XCD-aware bijective swizzle of the 2D block index (requires nwg % 8 == 0).
DEV void swz_block(int& bx, int& by) {
  const int nbx = gridDim.x;
  const int nwg = nbx * gridDim.y;
  const int lin = by * nbx + bx;
  const int cpx = nwg >> 3;
  const int swz = (lin & 7) * cpx + (lin >> 3);
  bx = swz % nbx;
  by = swz / nbx;
}

// EPI: 0 = bf16 store (+bias), 1 = fp32 residual add into xres, 2 = silu(gate)*acc
template <int EPI>
__global__ __launch_bounds__(256) void gemm_bt(
    const unsigned short* __restrict__ A, const unsigned short* __restrict__ W,
    const float* __restrict__ bias, unsigned short* __restrict__ outb,
    float* __restrict__ xres, const unsigned short* __restrict__ gate,
    int K, int ldo) {
  __shared__ unsigned short sA[4096];
  __shared__ unsigned short sB[4096];
  f32x4 acc[4][4] = {};
  int bx = blockIdx.x, by = blockIdx.y;
  swz_block(bx, by);
  const int m0 = by * 128, n0 = bx * 128;
  gemm_core(A, W, K, m0, n0, sA, sB, acc);
  const int lane = threadIdx.x & 63, wave = threadIdx.x >> 6;
  const int fr = lane & 15, r0 = (lane >> 4) * 4;
  const int wr = (wave >> 1) * 64, wc = (wave & 1) * 64;
#pragma unroll
  for (int mi = 0; mi < 4; ++mi)
#pragma unroll
    for (int ni = 0; ni < 4; ++ni)
#pragma unroll
      for (int r = 0; r < 4; ++r) {
        const int gm = m0 + wr + mi * 16 + r0 + r;
        const int gn = n0 + wc + ni * 16 + fr;
        float v = acc[mi][ni][r];
        if (EPI == 0) {
          if (bias) v += bias[gn];
          outb[(size_t)gm * ldo + gn] = f2bf(v);
        } else if (EPI == 1) {
          xres[(size_t)gm * ldo + gn] += v;
        } else {
          const float g = bf2f(gate[(size_t)gm * ldo + gn]);
          const float s = g / (1.f + __expf(-g));
          outb[(size_t)gm * ldo + gn] = f2bf(s * v);
        }
      }
}

// Fused QKV: col-tiles 0..15 -> q, 16..19 -> k, 20..23 -> v
__global__ __launch_bounds__(256) void gemm_qkv(
    const unsigned short* __restrict__ A, const unsigned short* __restrict__ qw,
    const float* __restrict__ qbias, const unsigned short* __restrict__ kw,
    const float* __restrict__ kbias, const unsigned short* __restrict__ vw,
    const float* __restrict__ vbias, unsigned short* __restrict__ qo,
    unsigned short* __restrict__ ko, unsigned short* __restrict__ vo) {
  __shared__ unsigned short sA[4096];
  __shared__ unsigned short sB[4096];
  int bx = blockIdx.x, by = blockIdx.y;
  swz_block(bx, by);
  const int ct = bx;
  const unsigned short* W; const float* bias; unsigned short* out; int n0, ldo;
  if (ct < 16)      { W = qw; bias = qbias; out = qo; n0 = ct * 128;        ldo = HIDDIM; }
  else if (ct < 20) { W = kw; bias = kbias; out = ko; n0 = (ct - 16) * 128; ldo = KVDIM; }
  else              { W = vw; bias = vbias; out = vo; n0 = (ct - 20) * 128; ldo = KVDIM; }
  f32x4 acc[4][4] = {};
  const int m0 = by * 128;
  gemm_core(A, W, HIDDIM, m0, n0, sA, sB, acc);
  const int lane = threadIdx.x & 63, wave = threadIdx.x >> 6;
  const int fr = lane & 15, r0 = (lane >> 4) * 4;
  const int wr = (wave >> 1) * 64, wc = (wave & 1) * 64;
#pragma unroll
  for (int mi = 0; mi < 4; ++mi)
#pragma unroll
    for (int ni = 0; ni < 4; ++ni)
#pragma unroll
      for (int r = 0; r < 4; ++r) {
        const int gm = m0 + wr + mi * 16 + r0 + r;
        const int gn = n0 + wc + ni * 16 + fr;
        out[(size_t)gm * ldo + gn] = f2bf(acc[mi][ni][r] + bias[gn]);
      }
}

// ---------------------------------------------------------------------------
// RoPE, in place on q (16 heads) and k (4 heads). 64 threads per (tok,head);
// thread d owns the (d, d+64) pair, so no sync needed.
// ---------------------------------------------------------------------------
__global__ __launch_bounds__(256) void rope_kernel(
    unsigned short* __restrict__ q, unsigned short* __restrict__ k,
    const float* __restrict__ cosb, const float* __restrict__ sinb) {
  const int slot = blockIdx.x * 4 + (threadIdx.x >> 6);
  const int d = threadIdx.x & 63;
  const int tok = slot / 20, hs = slot % 20;
  unsigned short* base;
  if (hs < 16) base = q + (size_t)tok * HIDDIM + hs * HDIM;
  else         base = k + (size_t)tok * KVDIM + (hs - 16) * HDIM;
  const float c1 = cosb[(size_t)tok * HDIM + d];
  const float s1 = sinb[(size_t)tok * HDIM + d];
  const float c2 = cosb[(size_t)tok * HDIM + d + 64];
  const float s2 = sinb[(size_t)tok * HDIM + d + 64];
  const float x1 = bf2f(base[d]), x2 = bf2f(base[d + 64]);
  base[d]      = f2bf(x1 * c1 - x2 * s1);
  base[d + 64] = f2bf(x2 * c2 + x1 * s2);
}

// v[tok][kvh*128+d] -> vt[(b*4+kvh)*128+d][t]   (output-coalesced)
__global__ __launch_bounds__(256) void transpose_v(
    const unsigned short* __restrict__ v, unsigned short* __restrict__ vt) {
  const int o = blockIdx.x * 256 + threadIdx.x;   // < 1048576
  const int t = o & 1023;
  const int rest = o >> 10;          // (b*4+kvh)*128 + d
  const int d = rest & 127;
  const int bh = rest >> 7;          // 0..7
  const int kvh = bh & 3, b = bh >> 2;
  vt[o] = v[(size_t)(b * 1024 + t) * KVDIM + kvh * HDIM + d];
}

// ---------------------------------------------------------------------------
// Flash attention, causal, GQA. Block = 4 waves; wave owns 16 q-rows.
// KV iterated in 64-col blocks; K/V read direct from global (L2-resident),
// P staged per-wave through LDS. fp32 online softmax.
// ---------------------------------------------------------------------------
__global__ __launch_bounds__(256) void attn_kernel(
    const unsigned short* __restrict__ q, const unsigned short* __restrict__ k,
    const unsigned short* __restrict__ vt, unsigned short* __restrict__ ao) {
  __shared__ unsigned short P_lds[4][1024];   // [wave][16q x 64kv]
  const int tid = threadIdx.x, lane = tid & 63, wave = tid >> 6;
  const int qt = blockIdx.x, h = blockIdx.y, b = blockIdx.z;
  const int kvh = h >> 2;
  const int q0 = qt * 64 + wave * 16;
  const int tokbase = b * 1024;
  const int fr = lane & 15, kq = (lane >> 4) * 8, r0 = (lane >> 4) * 4;

  bf16x8 aQ[4];
  {
    const unsigned short* qp =
        q + (size_t)(tokbase + q0 + fr) * HIDDIM + h * HDIM + kq;
#pragma unroll
    for (int ds = 0; ds < 4; ++ds)
      aQ[ds] = *reinterpret_cast<const bf16x8*>(qp + ds * 32);
  }
  float mrow[4], lrow[4];
#pragma unroll
  for (int r = 0; r < 4; ++r) { mrow[r] = -1e30f; lrow[r] = 0.f; }
  f32x4 accO[8] = {};
  const float scale = 0.08838834764831845f;   // 1/sqrt(128)
  const unsigned short* vbase = vt + (size_t)(b * 4 + kvh) * 128 * 1024;
  unsigned short* pw = &P_lds[wave][0];

  for (int kb = 0; kb <= qt; ++kb) {
    const int kv0 = kb * 64;
    f32x4 sacc[4] = {};
    const unsigned short* kbp =
        k + (size_t)(tokbase + kv0) * KVDIM + kvh * HDIM;
#pragma unroll
    for (int cb = 0; cb < 4; ++cb) {
      const unsigned short* kr = kbp + (size_t)(cb * 16 + fr) * KVDIM + kq;
#pragma unroll
      for (int ds = 0; ds < 4; ++ds) {
        bf16x8 bK = *reinterpret_cast<const bf16x8*>(kr + ds * 32);
        sacc[cb] =
            __builtin_amdgcn_mfma_f32_16x16x32_bf16(aQ[ds], bK, sacc[cb], 0, 0, 0);
      }
    }
    const bool maskblk = (kb == qt);
    float p[4][4];
#pragma unroll
    for (int r = 0; r < 4; ++r) {
      const int grow = q0 + r0 + r;
      float mx = -1e30f;
#pragma unroll
      for (int cb = 0; cb < 4; ++cb) {
        float s = sacc[cb][r] * scale;
        if (maskblk && (kv0 + cb * 16 + fr > grow)) s = -1e30f;
        p[cb][r] = s;
        mx = fmaxf(mx, s);
      }
#pragma unroll
      for (int off = 1; off < 16; off <<= 1)
        mx = fmaxf(mx, __shfl_xor(mx, off, 64));
      const float mn = fmaxf(mrow[r], mx);
      const float alpha = __expf(mrow[r] - mn);
      float sum = 0.f;
#pragma unroll
      for (int cb = 0; cb < 4; ++cb) {
        const float e = __expf(p[cb][r] - mn);
        p[cb][r] = e; sum += e;
      }
#pragma unroll
      for (int off = 1; off < 16; off <<= 1) sum += __shfl_xor(sum, off, 64);
      lrow[r] = lrow[r] * alpha + sum;
      mrow[r] = mn;
#pragma unroll
      for (int db = 0; db < 8; ++db) accO[db][r] *= alpha;
    }
    // P -> per-wave LDS (compiler orders ds_write -> ds_read via lgkmcnt)
#pragma unroll
    for (int cb = 0; cb < 4; ++cb)
#pragma unroll
      for (int r = 0; r < 4; ++r)
        pw[(r0 + r) * 64 + cb * 16 + fr] = f2bf(p[cb][r]);
    bf16x8 aP[2];
#pragma unroll
    for (int s2 = 0; s2 < 2; ++s2)
      aP[s2] = *reinterpret_cast<const bf16x8*>(pw + fr * 64 + s2 * 32 + kq);
#pragma unroll
    for (int db = 0; db < 8; ++db) {
      const unsigned short* vr = vbase + (size_t)(db * 16 + fr) * 1024 + kv0 + kq;
#pragma unroll
      for (int s2 = 0; s2 < 2; ++s2) {
        bf16x8 bV = *reinterpret_cast<const bf16x8*>(vr + s2 * 32);
        accO[db] =
            __builtin_amdgcn_mfma_f32_16x16x32_bf16(aP[s2], bV, accO[db], 0, 0, 0);
      }
    }
  }
  float invl[4];
#pragma unroll
  for (int r = 0; r < 4; ++r) invl[r] = 1.f / lrow[r];
#pragma unroll
  for (int db = 0; db < 8; ++db)
#pragma unroll
    for (int r = 0; r < 4; ++r)
      ao[(size_t)(tokbase + q0 + r0 + r) * HIDDIM + h * HDIM + db * 16 + fr] =
          f2bf(accO[db][r] * invl[r]);
}

// ---------------------------------------------------------------------------
extern "C" void kernel_launch(void* const* d_in, const int* in_sizes, int n_in,
                              void* d_out, int out_size, void* d_ws,
                              size_t ws_size, hipStream_t stream) {
  (void)in_sizes; (void)n_in; (void)out_size; (void)ws_size;
  const float* hidden = (const float*)d_in[0];
  const float* cosb  = (const float*)d_in[1];
  const float* sinb  = (const float*)d_in[2];
  const float* qw    = (const float*)d_in[3];
  const float* qbias = (const float*)d_in[4];
  const float* kw    = (const float*)d_in[5];
  const float* kbias = (const float*)d_in[6];
  const float* vw    = (const float*)d_in[7];
  const float* vbias = (const float*)d_in[8];
  const float* ow    = (const float*)d_in[9];
  const float* gw    = (const float*)d_in[10];
  const float* uw    = (const float*)d_in[11];
  const float* dw    = (const float*)d_in[12];
  const float* ln1   = (const float*)d_in[13];
  const float* ln2   = (const float*)d_in[14];
  const float* normw = (const float*)d_in[15];

  char* ws = (char*)d_ws;
  float* x               = (float*)ws;                          // 16,777,216 B
  unsigned short* hbuf   = (unsigned short*)(ws + 16777216);    //  8,388,608
  unsigned short* qbuf   = (unsigned short*)(ws + 25165824);    //  8,388,608
  unsigned short* kbuf   = (unsigned short*)(ws + 33554432);    //  2,097,152
  unsigned short* vbuf   = (unsigned short*)(ws + 35651584);    //  2,097,152
  unsigned short* vtbuf  = (unsigned short*)(ws + 37748736);    //  2,097,152
  unsigned short* aobuf  = (unsigned short*)(ws + 39845888);    //  8,388,608
  unsigned short* gatebuf= (unsigned short*)(ws + 48234496);    // 23,068,672
  unsigned short* actbuf = (unsigned short*)(ws + 71303168);    // 23,068,672
  unsigned short* wcvt   = (unsigned short*)(ws + 94371840);    // 23,068,672
  // total: 117,440,512 bytes

  // wcvt sub-allocations for the fused-QKV phase
  unsigned short* wq16 = wcvt;                 //  8,388,608 B (4.19M elems)
  unsigned short* wk16 = wcvt + 4194304;       //  2,097,152 B
  unsigned short* wv16 = wcvt + 5242880;       //  2,097,152 B

  hipMemcpyAsync(x, hidden, (size_t)NTOK * HIDDIM * 4,
                 hipMemcpyDeviceToDevice, stream);

  for (int l = 0; l < 4; ++l) {
    const float* qw_l = qw + (size_t)l * 2048 * 2048;
    const float* qb_l = qbias + (size_t)l * 2048;
    const float* kw_l = kw + (size_t)l * 512 * 2048;
    const float* kb_l = kbias + (size_t)l * 512;
    const float* vw_l = vw + (size_t)l * 512 * 2048;
    const float* vb_l = vbias + (size_t)l * 512;
    const float* ow_l = ow + (size_t)l * 2048 * 2048;
    const float* gw_l = gw + (size_t)l * 5632 * 2048;
    const float* uw_l = uw + (size_t)l * 5632 * 2048;
    const float* dw_l = dw + (size_t)l * 2048 * 5632;

    rmsnorm_kernel<0><<<NTOK, 256, 0, stream>>>(x, ln1 + l * 2048, hbuf);
    cvt_kernel<<<2048, 256, 0, stream>>>(qw_l, wq16, 524288);
    cvt_kernel<<<512, 256, 0, stream>>>(kw_l, wk16, 131072);
    cvt_kernel<<<512, 256, 0, stream>>>(vw_l, wv16, 131072);
    gemm_qkv<<<dim3(24, 16), 256, 0, stream>>>(hbuf, wq16, qb_l, wk16, kb_l,
                                               wv16, vb_l, qbuf, kbuf, vbuf);
    rope_kernel<<<10240, 256, 0, stream>>>(qbuf, kbuf, cosb, sinb);
    transpose_v<<<4096, 256, 0, stream>>>(vbuf, vtbuf);
    attn_kernel<<<dim3(16, 16, 2), 256, 0, stream>>>(qbuf, kbuf, vtbuf, aobuf);
    cvt_kernel<<<2048, 256, 0, stream>>>(ow_l, wcvt, 524288);
    gemm_bt<1><<<dim3(16, 16), 256, 0, stream>>>(aobuf, wcvt, nullptr, nullptr,
                                                 x, nullptr, 2048, 2048);
    rmsnorm_kernel<0><<<NTOK, 256, 0, stream>>>(x, ln2 + l * 2048, hbuf);
    cvt_kernel<<<5632, 256, 0, stream>>>(gw_l, wcvt, 1441792);
    gemm_bt<0><<<dim3(44, 16), 256, 0, stream>>>(hbuf, wcvt, nullptr, gatebuf,
                                                 nullptr, nullptr, 2048, 5632);
    cvt_kernel<<<5632, 256, 0, stream>>>(uw_l, wcvt, 1441792);
    gemm_bt<2><<<dim3(44, 16), 256, 0, stream>>>(hbuf, wcvt, nullptr, actbuf,
                                                 nullptr, gatebuf, 2048, 5632);
    cvt_kernel<<<5632, 256, 0, stream>>>(dw_l, wcvt, 1441792);
    gemm_bt<1><<<dim3(16, 16), 256, 0, stream>>>(actbuf, wcvt, nullptr, nullptr,
                                                 x, nullptr, 5632, 2048);
  }
  rmsnorm_kernel<1><<<NTOK, 256, 0, stream>>>(x, normw, d_out);
}

// Round 3
// 1970.092 us; speedup vs baseline: 1.5793x; 1.2299x over previous
//
#include <hip/hip_runtime.h>

// ---------------------------------------------------------------------------
// DecoderBackbone: 4-layer llama-style decoder, B=2 T=1024 HID=2048,
// NH=16 NKV=4 HD=128, INTER=5632. fp32 residual stream, bf16 MFMA GEMMs.
// R3: 256x256 8-phase counted-vmcnt GEMM (T2+T3+T4+T5) for gate/up/down/O,
// split-K for small-grid GEMMs, swizzled-source conflict-free LDS.
// ---------------------------------------------------------------------------

typedef __attribute__((ext_vector_type(8))) __bf16 bf16x8;
typedef __attribute__((ext_vector_type(4))) float f32x4;
typedef __attribute__((ext_vector_type(4))) unsigned short u16x4;

#define DEV __device__ __forceinline__

#define NTOK 2048     // B*T
#define HIDDIM 2048
#define NHEADS 16
#define NKVH 4
#define HDIM 128
#define KVDIM 512     // NKV*HD
#define INTERDIM 5632

DEV unsigned short f2bf(float f) {
  union { float f; unsigned u; } a; a.f = f;
  unsigned r = a.u + 0x7fffu + ((a.u >> 16) & 1u);   // RNE
  return (unsigned short)(r >> 16);
}
DEV float bf2f(unsigned short h) {
  union { unsigned u; float f; } a; a.u = ((unsigned)h) << 16;
  return a.f;
}
DEV void gload_lds16(const void* g, void* l) {
  __builtin_amdgcn_global_load_lds(
      (const __attribute__((address_space(1))) unsigned int*)(g),
      (__attribute__((address_space(3))) unsigned int*)(l), 16, 0, 0);
}

// ---------------------------------------------------------------------------
// fp32 -> bf16 weight convert, 8 elems/thread. n8 = n/8.
// ---------------------------------------------------------------------------
__global__ __launch_bounds__(256) void cvt_kernel(
    const float* __restrict__ in, unsigned short* __restrict__ out, int n8) {
  const int i = blockIdx.x * 256 + threadIdx.x;
  if (i >= n8) return;
  const f32x4* p = reinterpret_cast<const f32x4*>(in) + (size_t)i * 2;
  const f32x4 a = p[0], b = p[1];
  bf16x8 o;
  o[0] = (__bf16)a.x; o[1] = (__bf16)a.y; o[2] = (__bf16)a.z; o[3] = (__bf16)a.w;
  o[4] = (__bf16)b.x; o[5] = (__bf16)b.y; o[6] = (__bf16)b.z; o[7] = (__bf16)b.w;
  *reinterpret_cast<bf16x8*>(out + (size_t)i * 8) = o;
}

// ---------------------------------------------------------------------------
// RMSNorm: x fp32 [row][2048] -> out (bf16 or fp32), one block per row.
// ---------------------------------------------------------------------------
template <int OUTF32>
__global__ __launch_bounds__(256) void rmsnorm_kernel(
    const float* __restrict__ x, const float* __restrict__ w,
    void* __restrict__ outp) {
  const int row = blockIdx.x, tid = threadIdx.x;
  const int lane = tid & 63, wave = tid >> 6;
  const float* xr = x + (size_t)row * HIDDIM;
  f32x4 v0 = *reinterpret_cast<const f32x4*>(xr + tid * 4);
  f32x4 v1 = *reinterpret_cast<const f32x4*>(xr + 1024 + tid * 4);
  float ss = v0.x * v0.x + v0.y * v0.y + v0.z * v0.z + v0.w * v0.w +
             v1.x * v1.x + v1.y * v1.y + v1.z * v1.z + v1.w * v1.w;
#pragma unroll
  for (int off = 1; off < 64; off <<= 1) ss += __shfl_xor(ss, off, 64);
  __shared__ float red[4];
  if (lane == 0) red[wave] = ss;
  __syncthreads();
  ss = red[0] + red[1] + red[2] + red[3];
  const float rs = rsqrtf(ss * (1.0f / 2048.0f) + 1e-6f);
  f32x4 w0 = *reinterpret_cast<const f32x4*>(w + tid * 4);
  f32x4 w1 = *reinterpret_cast<const f32x4*>(w + 1024 + tid * 4);
  if (OUTF32) {
    float* o = (float*)outp + (size_t)row * HIDDIM;
    f32x4 o0, o1;
    o0.x = v0.x * rs * w0.x; o0.y = v0.y * rs * w0.y;
    o0.z = v0.z * rs * w0.z; o0.w = v0.w * rs * w0.w;
    o1.x = v1.x * rs * w1.x; o1.y = v1.y * rs * w1.y;
    o1.z = v1.z * rs * w1.z; o1.w = v1.w * rs * w1.w;
    *reinterpret_cast<f32x4*>(o + tid * 4) = o0;
    *reinterpret_cast<f32x4*>(o + 1024 + tid * 4) = o1;
  } else {
    unsigned short* o = (unsigned short*)outp + (size_t)row * HIDDIM;
    u16x4 p0, p1;
    p0.x = f2bf(v0.x * rs * w0.x); p0.y = f2bf(v0.y * rs * w0.y);
    p0.z = f2bf(v0.z * rs * w0.z); p0.w = f2bf(v0.w * rs * w0.w);
    p1.x = f2bf(v1.x * rs * w1.x); p1.y = f2bf(v1.y * rs * w1.y);
    p1.z = f2bf(v1.z * rs * w1.z); p1.w = f2bf(v1.w * rs * w1.w);
    *reinterpret_cast<u16x4*>(o + tid * 4) = p0;
    *reinterpret_cast<u16x4*>(o + 1024 + tid * 4) = p1;
  }
}

// ---------------------------------------------------------------------------
// 256x256 8-phase GEMM (T2+T3+T4+T5). C = A[M,K] * W[N,K]^T, bf16 in.
// 512 threads = 8 waves (2M x 4N), per-wave 128x64 out, BK=64, 2 K-tile LDS
// double-buffer (128 KiB). Staging: global_load_lds 16B, linear LDS dest,
// inverse-swizzled per-lane global source (col16 ^= row&7) == swizzle used
// on ds_read -> conflict-free b128 reads (rule #21 involution).
// Counted vmcnt(4) once per K-tile; per-phase barriers + setprio(1) around
// 16-MFMA clusters. EPI: 0=bf16(+bias), 2=silu(gate)*v bf16, 3=fp32 partial.
// ---------------------------------------------------------------------------
template <int MB>
DEV void mfma16(const bf16x8 (&aF)[4], const bf16x8 (&bF)[4],
                f32x4 (&acc)[8][4]) {
#pragma unroll
  for (int ni = 0; ni < 4; ++ni)
#pragma unroll
    for (int mi = 0; mi < 4; ++mi)
      acc[MB + mi][ni] = __builtin_amdgcn_mfma_f32_16x16x32_bf16(
          aF[mi], bF[ni], acc[MB + mi][ni], 0, 0, 0);
}

template <int EPI>
__global__ __launch_bounds__(512, 2) void gemm8p(
    const unsigned short* __restrict__ A, const unsigned short* __restrict__ W,
    const float* __restrict__ bias, unsigned short* __restrict__ outb,
    const unsigned short* __restrict__ gate, float* __restrict__ outf,
    int K, int ldo, int kt_split, int kt_tot, size_t zstride) {
  __shared__ unsigned short lds[65536];   // 128 KiB: [buf2][half4][128*64]
  const int tid = threadIdx.x, lane = tid & 63, wave = tid >> 6;
  const int fr = lane & 15, lq = lane >> 4;
  const int wm = wave >> 2, wn = wave & 3;

  int bx = blockIdx.x, by = blockIdx.y;
  {  // XCD-aware bijective swizzle within z-plane (nwg % 8 == 0 by construction)
    const int nbx = gridDim.x, nwg = nbx * gridDim.y;
    const int lin = by * nbx + bx, cpx = nwg >> 3;
    const int swz = (lin & 7) * cpx + (lin >> 3);
    bx = swz % nbx; by = swz / nbx;
  }
  const int m0 = by * 256, n0 = bx * 256;
  const int bz = blockIdx.z;
  const int t0 = bz * kt_split;
  int NT = kt_tot - t0; if (NT > kt_split) NT = kt_split;

  // --- staging per-thread source offsets (j = 0,1) ---
  const int u0 = tid, u1 = tid + 512;
  const int r0s = u0 >> 3, r1s = u1 >> 3;
  const size_t off0 = (size_t)r0s * K + (size_t)((((u0 & 7) ^ (r0s & 7))) << 3);
  const size_t off1 = (size_t)r1s * K + (size_t)((((u1 & 7) ^ (r1s & 7))) << 3);
  const unsigned short* gb0 = A + (size_t)(m0)*K + (size_t)t0 * 64;
  const unsigned short* gb1 = A + (size_t)(m0 + 128) * K + (size_t)t0 * 64;
  const unsigned short* gb2 = W + (size_t)(n0)*K + (size_t)t0 * 64;
  const unsigned short* gb3 = W + (size_t)(n0 + 128) * K + (size_t)t0 * 64;

#define STAGE(h_, tt_, b_)                                                    \
  do {                                                                        \
    const unsigned short* _g =                                                \
        ((h_) == 0 ? gb0 : (h_) == 1 ? gb1 : (h_) == 2 ? gb2 : gb3) +         \
        (size_t)(tt_)*64;                                                     \
    unsigned short* _l = &lds[(b_)*32768 + (h_)*8192 + wave * 512];           \
    gload_lds16(_g + off0, _l);                                               \
    gload_lds16(_g + off1, _l + 4096);                                        \
  } while (0)

  // --- ds_read fragment addresses (swizzled): unit = row*8 + (g ^ (row&7)) ---
  const int e0 = lq ^ (fr & 7);
  const int cbA = wm * 8192;                 // + c*32768; row = mi*16 + fr
  const int cbB = (2 + (wn >> 1)) * 8192;    // row = (wn&1)*64 + ni*16 + fr
  const int rB0 = (wn & 1) * 64 + fr;

#define LDA(mi_, ks_, c_)                                                     \
  (*reinterpret_cast<const bf16x8*>(                                          \
      &lds[(c_)*32768 + cbA + ((mi_)*16 + fr) * 64 + ((e0 ^ ((ks_)*4)) << 3)]))
#define LDB(ni_, ks_, c_)                                                     \
  (*reinterpret_cast<const bf16x8*>(                                          \
      &lds[(c_)*32768 + cbB + (rB0 + (ni_)*16) * 64 + ((e0 ^ ((ks_)*4)) << 3)]))

#define BARRIER() asm volatile("s_barrier" ::: "memory")

  f32x4 acc[8][4] = {};
  bf16x8 aF[4], bF[4];

  // prologue: stage K-tile 0 fully into buf 0
  STAGE(0, 0, 0); STAGE(1, 0, 0); STAGE(2, 0, 0); STAGE(3, 0, 0);

  for (int t = 0; t < NT; ++t) {
    const int c = t & 1;
    // K-tile top: issue A0/B0 of t+1 (their regions' last read ended at the
    // barrier closing t-1), then counted wait: tile t landed, 4 stay in flight.
    if (t + 1 < NT) {
      STAGE(0, t + 1, c ^ 1);
      STAGE(2, t + 1, c ^ 1);
      asm volatile("s_waitcnt vmcnt(4)" ::: "memory");
    } else {
      asm volatile("s_waitcnt vmcnt(0)" ::: "memory");
    }
    BARRIER();

    // phase 1: ks0, mi 0-3 (+B ks0); stage A1/B1 of t+1
    bF[0] = LDB(0, 0, c); bF[1] = LDB(1, 0, c);
    bF[2] = LDB(2, 0, c); bF[3] = LDB(3, 0, c);
    aF[0] = LDA(0, 0, c); aF[1] = LDA(1, 0, c);
    aF[2] = LDA(2, 0, c); aF[3] = LDA(3, 0, c);
    if (t + 1 < NT) { STAGE(1, t + 1, c ^ 1); STAGE(3, t + 1, c ^ 1); }
    BARRIER();
    __builtin_amdgcn_s_setprio(1);
    mfma16<0>(aF, bF, acc);
    __builtin_amdgcn_s_setprio(0);
    __builtin_amdgcn_sched_barrier(0);
    BARRIER();

    // phase 2: ks0, mi 4-7
    aF[0] = LDA(4, 0, c); aF[1] = LDA(5, 0, c);
    aF[2] = LDA(6, 0, c); aF[3] = LDA(7, 0, c);
    BARRIER();
    __builtin_amdgcn_s_setprio(1);
    mfma16<4>(aF, bF, acc);
    __builtin_amdgcn_s_setprio(0);
    __builtin_amdgcn_sched_barrier(0);
    BARRIER();

    // phase 3: ks1, mi 0-3 (+B ks1)
    bF[0] = LDB(0, 1, c); bF[1] = LDB(1, 1, c);
    bF[2] = LDB(2, 1, c); bF[3] = LDB(3, 1, c);
    aF[0] = LDA(0, 1, c); aF[1] = LDA(1, 1, c);
    aF[2] = LDA(2, 1, c); aF[3] = LDA(3, 1, c);
    BARRIER();
    __builtin_amdgcn_s_setprio(1);
    mfma16<0>(aF, bF, acc);
    __builtin_amdgcn_s_setprio(0);
    __builtin_amdgcn_sched_barrier(0);
    BARRIER();

    // phase 4: ks1, mi 4-7
    aF[0] = LDA(4, 1, c); aF[1] = LDA(5, 1, c);
    aF[2] = LDA(6, 1, c); aF[3] = LDA(7, 1, c);
    BARRIER();
    __builtin_amdgcn_s_setprio(1);
    mfma16<4>(aF, bF, acc);
    __builtin_amdgcn_s_setprio(0);
    __builtin_amdgcn_sched_barrier(0);
    BARRIER();
  }

  // epilogue
  const int r0 = lq * 4;
#pragma unroll
  for (int mi = 0; mi < 8; ++mi)
#pragma unroll
    for (int ni = 0; ni < 4; ++ni)
#pragma unroll
      for (int r = 0; r < 4; ++r) {
        const int gm = m0 + wm * 128 + mi * 16 + r0 + r;
        const int gn = n0 + wn * 64 + ni * 16 + fr;
        const float v = acc[mi][ni][r];
        if (EPI == 0) {
          float vv = v;
          if (bias) vv += bias[gn];
          outb[(size_t)gm * ldo + gn] = f2bf(vv);
        } else if (EPI == 2) {
          const float g = bf2f(gate[(size_t)gm * ldo + gn]);
          const float s = g / (1.f + __expf(-g));
          outb[(size_t)gm * ldo + gn] = f2bf(s * v);
        } else {
          outf[(size_t)bz * zstride + (size_t)gm * ldo + gn] = v;
        }
      }
#undef STAGE
#undef LDA
#undef LDB
#undef BARRIER
}

// x[i] += sum_{s<ks} p[s*zs4*4 + i]  (f32x4 lanes; n4 = n/4, zs4 = zstride/4)
__global__ __launch_bounds__(256) void reduce_addk(
    float* __restrict__ x, const float* __restrict__ p, int n4, int ks,
    size_t zs4) {
  const f32x4* pv = reinterpret_cast<const f32x4*>(p);
  f32x4* xv = reinterpret_cast<f32x4*>(x);
  for (int i = blockIdx.x * 256 + threadIdx.x; i < n4; i += gridDim.x * 256) {
    f32x4 s = pv[i];
    for (int sp = 1; sp < ks; ++sp) s += pv[(size_t)sp * zs4 + i];
    xv[i] += s;
  }
}

// ---------------------------------------------------------------------------
// m97-structure 128x128 GEMM core (kept for fused QKV this round).
// ---------------------------------------------------------------------------
DEV void gemm_core(const unsigned short* __restrict__ A,
                   const unsigned short* __restrict__ Wb, int K, int m0, int n0,
                   unsigned short* sA, unsigned short* sB,
                   f32x4 (&acc)[4][4]) {
  const int tid = threadIdx.x;
  const int lane = tid & 63, wave = tid >> 6;
  const int fr = lane & 15, kq = (lane >> 4) * 8;
  const int wr = (wave >> 1) * 64, wc = (wave & 1) * 64;
  const int row = tid >> 2, kk = (tid & 3) * 8;
  const unsigned short* Ag0 = A + (size_t)(m0 + row) * K + kk;
  const unsigned short* Ag1 = Ag0 + (size_t)64 * K;
  const unsigned short* Bg0 = Wb + (size_t)(n0 + row) * K + kk;
  const unsigned short* Bg1 = Bg0 + (size_t)64 * K;
  unsigned short* sA0 = sA + wave * 512;
  unsigned short* sA1 = sA + 2048 + wave * 512;
  unsigned short* sB0 = sB + wave * 512;
  unsigned short* sB1 = sB + 2048 + wave * 512;

  for (int k0 = 0; k0 < K; k0 += 32) {
    gload_lds16(Ag0 + k0, sA0);
    gload_lds16(Ag1 + k0, sA1);
    gload_lds16(Bg0 + k0, sB0);
    gload_lds16(Bg1 + k0, sB1);
    __syncthreads();
    bf16x8 af[4], bfr[4];
#pragma unroll
    for (int i = 0; i < 4; ++i)
      af[i] = *reinterpret_cast<const bf16x8*>(sA + (wr + i * 16 + fr) * 32 + kq);
#pragma unroll
    for (int i = 0; i < 4; ++i)
      bfr[i] = *reinterpret_cast<const bf16x8*>(sB + (wc + i * 16 + fr) * 32 + kq);
#pragma unroll
    for (int mi = 0; mi < 4; ++mi)
#pragma unroll
      for (int ni = 0; ni < 4; ++ni)
        acc[mi][ni] = __builtin_amdgcn_mfma_f32_16x16x32_bf16(
            af[mi], bfr[ni], acc[mi][ni], 0, 0, 0);
    __syncthreads();
  }
}

DEV void swz_block(int& bx, int& by) {
  const int nbx = gridDim.x;
  const int nwg = nbx * gridDim.y;
  const int lin = by * nbx + bx;
  const int cpx = nwg >> 3;
  const int swz = (lin & 7) * cpx + (lin >> 3);
  bx = swz % nbx;
  by = swz / nbx;
}

// Fused QKV: col-tiles 0..15 -> q, 16..19 -> k, 20..23 -> v
__global__ __launch_bounds__(256) void gemm_qkv(
    const unsigned short* __restrict__ A, const unsigned short* __restrict__ qw,
    const float* __restrict__ qbias, const unsigned short* __restrict__ kw,
    const float* __restrict__ kbias, const unsigned short* __restrict__ vw,
    const float* __restrict__ vbias, unsigned short* __restrict__ qo,
    unsigned short* __restrict__ ko, unsigned short* __restrict__ vo) {
  __shared__ unsigned short sA[4096];
  __shared__ unsigned short sB[4096];
  int bx = blockIdx.x, by = blockIdx.y;
  swz_block(bx, by);
  const int ct = bx;
  const unsigned short* W; const float* bias; unsigned short* out; int n0, ldo;
  if (ct < 16)      { W = qw; bias = qbias; out = qo; n0 = ct * 128;        ldo = HIDDIM; }
  else if (ct < 20) { W = kw; bias = kbias; out = ko; n0 = (ct - 16) * 128; ldo = KVDIM; }
  else              { W = vw; bias = vbias; out = vo; n0 = (ct - 20) * 128; ldo = KVDIM; }
  f32x4 acc[4][4] = {};
  const int m0 = by * 128;
  gemm_core(A, W, HIDDIM, m0, n0, sA, sB, acc);
  const int lane = threadIdx.x & 63, wave = threadIdx.x >> 6;
  const int fr = lane & 15, r0 = (lane >> 4) * 4;
  const int wr = (wave >> 1) * 64, wc = (wave & 1) * 64;
#pragma unroll
  for (int mi = 0; mi < 4; ++mi)
#pragma unroll
    for (int ni = 0; ni < 4; ++ni)
#pragma unroll
      for (int r = 0; r < 4; ++r) {
        const int gm = m0 + wr + mi * 16 + r0 + r;
        const int gn = n0 + wc + ni * 16 + fr;
        out[(size_t)gm * ldo + gn] = f2bf(acc[mi][ni][r] + bias[gn]);
      }
}

// ---------------------------------------------------------------------------
// RoPE, in place on q (16 heads) and k (4 heads).
// ---------------------------------------------------------------------------
__global__ __launch_bounds__(256) void rope_kernel(
    unsigned short* __restrict__ q, unsigned short* __restrict__ k,
    const float* __restrict__ cosb, const float* __restrict__ sinb) {
  const int slot = blockIdx.x * 4 + (threadIdx.x >> 6);
  const int d = threadIdx.x & 63;
  const int tok = slot / 20, hs = slot % 20;
  unsigned short* base;
  if (hs < 16) base = q + (size_t)tok * HIDDIM + hs * HDIM;
  else         base = k + (size_t)tok * KVDIM + (hs - 16) * HDIM;
  const float c1 = cosb[(size_t)tok * HDIM + d];
  const float s1 = sinb[(size_t)tok * HDIM + d];
  const float c2 = cosb[(size_t)tok * HDIM + d + 64];
  const float s2 = sinb[(size_t)tok * HDIM + d + 64];
  const float x1 = bf2f(base[d]), x2 = bf2f(base[d + 64]);
  base[d]      = f2bf(x1 * c1 - x2 * s1);
  base[d + 64] = f2bf(x2 * c2 + x1 * s2);
}

// v[tok][kvh*128+d] -> vt[(b*4+kvh)*128+d][t]
__global__ __launch_bounds__(256) void transpose_v(
    const unsigned short* __restrict__ v, unsigned short* __restrict__ vt) {
  const int o = blockIdx.x * 256 + threadIdx.x;
  const int t = o & 1023;
  const int rest = o >> 10;
  const int d = rest & 127;
  const int bh = rest >> 7;
  const int kvh = bh & 3, b = bh >> 2;
  vt[o] = v[(size_t)(b * 1024 + t) * KVDIM + kvh * HDIM + d];
}

// ---------------------------------------------------------------------------
// Flash attention, causal, GQA (unchanged this round).
// ---------------------------------------------------------------------------
__global__ __launch_bounds__(256) void attn_kernel(
    const unsigned short* __restrict__ q, const unsigned short* __restrict__ k,
    const unsigned short* __restrict__ vt, unsigned short* __restrict__ ao) {
  __shared__ unsigned short P_lds[4][1024];
  const int tid = threadIdx.x, lane = tid & 63, wave = tid >> 6;
  const int qt = blockIdx.x, h = blockIdx.y, b = blockIdx.z;
  const int kvh = h >> 2;
  const int q0 = qt * 64 + wave * 16;
  const int tokbase = b * 1024;
  const int fr = lane & 15, kq = (lane >> 4) * 8, r0 = (lane >> 4) * 4;

  bf16x8 aQ[4];
  {
    const unsigned short* qp =
        q + (size_t)(tokbase + q0 + fr) * HIDDIM + h * HDIM + kq;
#pragma unroll
    for (int ds = 0; ds < 4; ++ds)
      aQ[ds] = *reinterpret_cast<const bf16x8*>(qp + ds * 32);
  }
  float mrow[4], lrow[4];
#pragma unroll
  for (int r = 0; r < 4; ++r) { mrow[r] = -1e30f; lrow[r] = 0.f; }
  f32x4 accO[8] = {};
  const float scale = 0.08838834764831845f;
  const unsigned short* vbase = vt + (size_t)(b * 4 + kvh) * 128 * 1024;
  unsigned short* pw = &P_lds[wave][0];

  for (int kb = 0; kb <= qt; ++kb) {
    const int kv0 = kb * 64;
    f32x4 sacc[4] = {};
    const unsigned short* kbp =
        k + (size_t)(tokbase + kv0) * KVDIM + kvh * HDIM;
#pragma unroll
    for (int cb = 0; cb < 4; ++cb) {
      const unsigned short* kr = kbp + (size_t)(cb * 16 + fr) * KVDIM + kq;
#pragma unroll
      for (int ds = 0; ds < 4; ++ds) {
        bf16x8 bK = *reinterpret_cast<const bf16x8*>(kr + ds * 32);
        sacc[cb] =
            __builtin_amdgcn_mfma_f32_16x16x32_bf16(aQ[ds], bK, sacc[cb], 0, 0, 0);
      }
    }
    const bool maskblk = (kb == qt);
    float p[4][4];
#pragma unroll
    for (int r = 0; r < 4; ++r) {
      const int grow = q0 + r0 + r;
      float mx = -1e30f;
#pragma unroll
      for (int cb = 0; cb < 4; ++cb) {
        float s = sacc[cb][r] * scale;
        if (maskblk && (kv0 + cb * 16 + fr > grow)) s = -1e30f;
        p[cb][r] = s;
        mx = fmaxf(mx, s);
      }
#pragma unroll
      for (int off = 1; off < 16; off <<= 1)
        mx = fmaxf(mx, __shfl_xor(mx, off, 64));
      const float mn = fmaxf(mrow[r], mx);
      const float alpha = __expf(mrow[r] - mn);
      float sum = 0.f;
#pragma unroll
      for (int cb = 0; cb < 4; ++cb) {
        const float e = __expf(p[cb][r] - mn);
        p[cb][r] = e; sum += e;
      }
#pragma unroll
      for (int off = 1; off < 16; off <<= 1) sum += __shfl_xor(sum, off, 64);
      lrow[r] = lrow[r] * alpha + sum;
      mrow[r] = mn;
#pragma unroll
      for (int db = 0; db < 8; ++db) accO[db][r] *= alpha;
    }
#pragma unroll
    for (int cb = 0; cb < 4; ++cb)
#pragma unroll
      for (int r = 0; r < 4; ++r)
        pw[(r0 + r) * 64 + cb * 16 + fr] = f2bf(p[cb][r]);
    bf16x8 aP[2];
#pragma unroll
    for (int s2 = 0; s2 < 2; ++s2)
      aP[s2] = *reinterpret_cast<const bf16x8*>(pw + fr * 64 + s2 * 32 + kq);
#pragma unroll
    for (int db = 0; db < 8; ++db) {
      const unsigned short* vr = vbase + (size_t)(db * 16 + fr) * 1024 + kv0 + kq;
#pragma unroll
      for (int s2 = 0; s2 < 2; ++s2) {
        bf16x8 bV = *reinterpret_cast<const bf16x8*>(vr + s2 * 32);
        accO[db] =
            __builtin_amdgcn_mfma_f32_16x16x32_bf16(aP[s2], bV, accO[db], 0, 0, 0);
      }
    }
  }
  float invl[4];
#pragma unroll
  for (int r = 0; r < 4; ++r) invl[r] = 1.f / lrow[r];
#pragma unroll
  for (int db = 0; db < 8; ++db)
#pragma unroll
    for (int r = 0; r < 4; ++r)
      ao[(size_t)(tokbase + q0 + r0 + r) * HIDDIM + h * HDIM + db * 16 + fr] =
          f2bf(accO[db][r] * invl[r]);
}

// ---------------------------------------------------------------------------
extern "C" void kernel_launch(void* const* d_in, const int* in_sizes, int n_in,
                              void* d_out, int out_size, void* d_ws,
                              size_t ws_size, hipStream_t stream) {
  (void)in_sizes; (void)n_in; (void)out_size; (void)ws_size;
  const float* hidden = (const float*)d_in[0];
  const float* cosb  = (const float*)d_in[1];
  const float* sinb  = (const float*)d_in[2];
  const float* qw    = (const float*)d_in[3];
  const float* qbias = (const float*)d_in[4];
  const float* kw    = (const float*)d_in[5];
  const float* kbias = (const float*)d_in[6];
  const float* vw    = (const float*)d_in[7];
  const float* vbias = (const float*)d_in[8];
  const float* ow    = (const float*)d_in[9];
  const float* gw    = (const float*)d_in[10];
  const float* uw    = (const float*)d_in[11];
  const float* dw    = (const float*)d_in[12];
  const float* ln1   = (const float*)d_in[13];
  const float* ln2   = (const float*)d_in[14];
  const float* normw = (const float*)d_in[15];

  char* ws = (char*)d_ws;
  float* x               = (float*)ws;                          // 16,777,216 B
  unsigned short* hbuf   = (unsigned short*)(ws + 16777216);    //  8,388,608
  unsigned short* qbuf   = (unsigned short*)(ws + 25165824);    //  8,388,608
  unsigned short* kbuf   = (unsigned short*)(ws + 33554432);    //  2,097,152
  unsigned short* vbuf   = (unsigned short*)(ws + 35651584);    //  2,097,152
  unsigned short* vtbuf  = (unsigned short*)(ws + 37748736);    //  2,097,152
  unsigned short* aobuf  = (unsigned short*)(ws + 39845888);    //  8,388,608
  unsigned short* gatebuf= (unsigned short*)(ws + 48234496);    // 23,068,672
  unsigned short* actbuf = (unsigned short*)(ws + 71303168);    // 23,068,672
  unsigned short* wcvt   = (unsigned short*)(ws + 94371840);    // 23,068,672
  // total: 117,440,512 bytes
  //
  // Split-K fp32 partials reuse DEAD regions:
  //  - O-proj (KS=2, 33.5 MB): [gatebuf .. inside actbuf) — both dead there.
  //  - down   (KS=3, 50.3 MB): [hbuf .. gatebuf end)      — all dead there.
  float* pbufO = (float*)(ws + 48234496);
  float* pbufD = (float*)(ws + 16777216);

  unsigned short* wq16 = wcvt;
  unsigned short* wk16 = wcvt + 4194304;
  unsigned short* wv16 = wcvt + 5242880;

  hipMemcpyAsync(x, hidden, (size_t)NTOK * HIDDIM * 4,
                 hipMemcpyDeviceToDevice, stream);

  for (int l = 0; l < 4; ++l) {
    const float* qw_l = qw + (size_t)l * 2048 * 2048;
    const float* qb_l = qbias + (size_t)l * 2048;
    const float* kw_l = kw + (size_t)l * 512 * 2048;
    const float* kb_l = kbias + (size_t)l * 512;
    const float* vw_l = vw + (size_t)l * 512 * 2048;
    const float* vb_l = vbias + (size_t)l * 512;
    const float* ow_l = ow + (size_t)l * 2048 * 2048;
    const float* gw_l = gw + (size_t)l * 5632 * 2048;
    const float* uw_l = uw + (size_t)l * 5632 * 2048;
    const float* dw_l = dw + (size_t)l * 2048 * 5632;

    rmsnorm_kernel<0><<<NTOK, 256, 0, stream>>>(x, ln1 + l * 2048, hbuf);
    cvt_kernel<<<2048, 256, 0, stream>>>(qw_l, wq16, 524288);
    cvt_kernel<<<512, 256, 0, stream>>>(kw_l, wk16, 131072);
    cvt_kernel<<<512, 256, 0, stream>>>(vw_l, wv16, 131072);
    gemm_qkv<<<dim3(24, 16), 256, 0, stream>>>(hbuf, wq16, qb_l, wk16, kb_l,
                                               wv16, vb_l, qbuf, kbuf, vbuf);
    rope_kernel<<<10240, 256, 0, stream>>>(qbuf, kbuf, cosb, sinb);
    transpose_v<<<4096, 256, 0, stream>>>(vbuf, vtbuf);
    attn_kernel<<<dim3(16, 16, 2), 256, 0, stream>>>(qbuf, kbuf, vtbuf, aobuf);

    // O-proj: split-K2 8-phase -> fp32 partials -> x += sum
    cvt_kernel<<<2048, 256, 0, stream>>>(ow_l, wcvt, 524288);
    gemm8p<3><<<dim3(8, 8, 2), 512, 0, stream>>>(
        aobuf, wcvt, nullptr, nullptr, nullptr, pbufO, 2048, 2048, 16, 32,
        (size_t)4194304);
    reduce_addk<<<2048, 256, 0, stream>>>(x, pbufO, 1048576, 2,
                                          (size_t)1048576);

    rmsnorm_kernel<0><<<NTOK, 256, 0, stream>>>(x, ln2 + l * 2048, hbuf);

    // gate
    cvt_kernel<<<5632, 256, 0, stream>>>(gw_l, wcvt, 1441792);
    gemm8p<0><<<dim3(22, 8, 1), 512, 0, stream>>>(
        hbuf, wcvt, nullptr, gatebuf, nullptr, nullptr, 2048, 5632, 32, 32,
        (size_t)0);
    // up (+ silu(gate) epilogue)
    cvt_kernel<<<5632, 256, 0, stream>>>(uw_l, wcvt, 1441792);
    gemm8p<2><<<dim3(22, 8, 1), 512, 0, stream>>>(
        hbuf, wcvt, nullptr, actbuf, gatebuf, nullptr, 2048, 5632, 32, 32,
        (size_t)0);
    // down: split-K3 -> fp32 partials -> x += sum
    cvt_kernel<<<5632, 256, 0, stream>>>(dw_l, wcvt, 1441792);
    gemm8p<3><<<dim3(8, 8, 3), 512, 0, stream>>>(
        actbuf, wcvt, nullptr, nullptr, nullptr, pbufD, 5632, 2048, 30, 88,
        (size_t)4194304);
    reduce_addk<<<2048, 256, 0, stream>>>(x, pbufD, 1048576, 3,
                                          (size_t)1048576);
  }
  rmsnorm_kernel<1><<<NTOK, 256, 0, stream>>>(x, normw, d_out);
}